// Round 3
// baseline (1158.679 us; speedup 1.0000x reference)
//
#include <hip/hip_runtime.h>

#define N_TOK 131072
#define DIM   256
#define KCB   1024

#define RPB   256          // rows per block (8 waves x 32 rows)
#define NSTG  8            // codebook stages of 128 codes (64KB fp16 each)
#define TAU   0.02f        // candidate margin; ~8x worst-case |dv - dv_fp32| for fp16 plane
#define ECAP  126          // per-wave per-stage emission capacity
#define CB_SCALE 4096.0f   // exact pow2 pre-scale of codebook before fp16
#define ACC_SCL  4.8828125e-4f   // 2/4096 exact pow2: dv = cc - acc*ACC_SCL

typedef __attribute__((ext_vector_type(8))) _Float16 f16x8;
typedef __attribute__((ext_vector_type(4))) float f32x4;

// async global->LDS, 16B per lane; LDS dest = wave-uniform base + lane*16
__device__ __forceinline__ void gload_lds16(const short* g, short* l) {
  __builtin_amdgcn_global_load_lds(
      (const __attribute__((address_space(1))) void*)g,
      (__attribute__((address_space(3))) void*)l, 16, 0, 0);
}

// Bit-exact replica of numpy pairwise_sum over 128 floats of x*x.
__device__ __forceinline__ float np_sumsq_128(const float* __restrict__ p) {
#pragma clang fp contract(off)
  float4 a = *(const float4*)(p);
  float4 b = *(const float4*)(p + 4);
  float r0 = a.x * a.x, r1 = a.y * a.y, r2 = a.z * a.z, r3 = a.w * a.w;
  float r4 = b.x * b.x, r5 = b.y * b.y, r6 = b.z * b.z, r7 = b.w * b.w;
  for (int i = 8; i < 128; i += 8) {
    float4 c = *(const float4*)(p + i);
    float4 d = *(const float4*)(p + i + 4);
    r0 += c.x * c.x; r1 += c.y * c.y; r2 += c.z * c.z; r3 += c.w * c.w;
    r4 += d.x * d.x; r5 += d.y * d.y; r6 += d.z * d.z; r7 += d.w * d.w;
  }
  return ((r0 + r1) + (r2 + r3)) + ((r4 + r5) + (r6 + r7));
}

// exact fp32 distance, identical bits to prior verified rounds:
// dd = (zz_np - 2*fmaf_chain_dot) + cc_np
__device__ __forceinline__ float exact_dd(const float* __restrict__ zp,
                                          const float* __restrict__ cp,
                                          float cc) {
  float zz = np_sumsq_128(zp) + np_sumsq_128(zp + 128);
  float dot = 0.f;
  for (int d = 0; d < DIM; d += 4) {
    float4 zv = *(const float4*)(zp + d);
    float4 cv = *(const float4*)(cp + d);
    dot = fmaf(zv.x, cv.x, dot); dot = fmaf(zv.y, cv.y, dot);
    dot = fmaf(zv.z, cv.z, dot); dot = fmaf(zv.w, cv.w, dot);
  }
  return (zz - 2.0f * dot) + cc;
}

// K0a: ||c_k||^2 (bit-exact) + zero the loss partial slots.
__global__ void prep_cc(const float* __restrict__ cb, float* __restrict__ cc,
                        double* __restrict__ slots, int nslots) {
  int gid = blockIdx.x * blockDim.x + threadIdx.x;
  for (int i = gid; i < nslots; i += 1024) slots[i] = 0.0;
  if (gid < KCB) {
    const float* p = cb + (long)gid * DIM;
    cc[gid] = np_sumsq_128(p) + np_sumsq_128(p + 128);
  }
}

// K0b: codebook -> fp16 (scaled by 4096), fragment-major stage layout, and
// init the packed (dd_bits<<32|k) argmin array to ~0.
// o bits: dl(0..2) k15(3..6) qd(7..8) ds(9..11) cf(12..15) q(16..17)
//   k = q*256 + cf*16 + k15,  d = ds*32 + qd*8 + dl
// Stage s (128 codes) = contiguous 64KB at s*32768 shorts -> linear staging,
// every B-frag ds_read_b128 is a linear conflict-free 1KB wave read.
__global__ void prep_h16(const float* __restrict__ cb, short* __restrict__ ch,
                         unsigned long long* __restrict__ packed) {
  int o = blockIdx.x * blockDim.x + threadIdx.x;
  if (o < N_TOK) packed[o] = ~0ull;
  if (o < KCB * DIM) {
    int dl = o & 7, k15 = (o >> 3) & 15, qd = (o >> 7) & 3;
    int ds = (o >> 9) & 7, cf = (o >> 12) & 15, q = (o >> 16) & 3;
    int k = q * 256 + cf * 16 + k15;
    int d = ds * 32 + qd * 8 + dl;
    float v = cb[k * DIM + d] * CB_SCALE;   // exact pow2 scale
    ((_Float16*)ch)[o] = (_Float16)v;       // RTNE
  }
}

// K1: codebook-stage-resident VQ argmin. 8 waves x 32 rows, z A-frags and
// running row-min in registers; 2 barriers per 128-code stage; emission vs
// register running-min; exact fp32 recheck -> packed u64 global atomicMin.
__global__ __launch_bounds__(512, 2)
void vq_kernel(const float* __restrict__ z, const float* __restrict__ cb,
               const short* __restrict__ ch_g, const float* __restrict__ cc_g,
               unsigned long long* __restrict__ packed) {
  __shared__ __align__(16) short cbuf[32768];     // 64KB: [cf8][ds8][512]
  __shared__ __align__(16) float cc_s[KCB];       // 4KB (exact cc bits)
  __shared__ unsigned emit_s[8][ECAP + 2];        // [wave][0]=count, entries at 1..

  const int t    = threadIdx.x;
  const int lane = t & 63;
  const int wv   = t >> 6;       // wave 0..7, owns rows 32*wv .. 32*wv+31
  const int l15  = lane & 15;
  const int qd   = lane >> 4;    // quad 0..3
  const long rowbase = (long)blockIdx.x * RPB;

  // ---- prologue: stage stage-0 codebook + cc into LDS ----
#pragma unroll
  for (int j = 0; j < 8; ++j) {
    int off = wv * 4096 + j * 512 + lane * 8;
    gload_lds16(ch_g + off, &cbuf[0] + off);
  }
  if (wv < 4) {
    int off = wv * 512 + lane * 8;
    gload_lds16((const short*)cc_g + off, (short*)cc_s + off);
  }
  if (lane == 0) emit_s[wv][0] = 0u;

  // ---- z A-fragments: load + fp16 convert ONCE, kept in VGPRs ----
  // lane holds z[row = 32*wv + 16*m + l15][ds*32 + qd*8 .. +7]
  f16x8 a16[2][8];
  {
    const float* zp0 = z + (rowbase + 32 * wv + l15) * (long)DIM + qd * 8;
#pragma unroll
    for (int m = 0; m < 2; ++m) {
      const float* zp = zp0 + m * 16 * DIM;
#pragma unroll
      for (int ds = 0; ds < 8; ++ds) {
        float4 v0 = *(const float4*)(zp + ds * 32);
        float4 v1 = *(const float4*)(zp + ds * 32 + 4);
        float f[8] = {v0.x, v0.y, v0.z, v0.w, v1.x, v1.y, v1.z, v1.w};
#pragma unroll
        for (int j = 0; j < 8; ++j) a16[m][ds][j] = (_Float16)f[j];  // RTNE
      }
    }
  }

  // running per-row min of dv (register-resident; rows are wave-private)
  float runmin[2][4];
#pragma unroll
  for (int m = 0; m < 2; ++m)
#pragma unroll
    for (int rg = 0; rg < 4; ++rg) runmin[m][rg] = __builtin_inff();

  __syncthreads();   // stage 0 + cc staged (barrier drains vmcnt)

#pragma clang loop unroll(disable)
  for (int s = 0; s < NSTG; ++s) {
    const int kbase = s * 128;
    // ---- MFMA: 128 codes x 32 rows x 256 dims, no sync ----
    f32x4 acc[2][8];
#pragma unroll
    for (int m = 0; m < 2; ++m)
#pragma unroll
      for (int c = 0; c < 8; ++c) acc[m][c] = (f32x4){0.f, 0.f, 0.f, 0.f};
#pragma unroll
    for (int ds = 0; ds < 8; ++ds) {
#pragma unroll
      for (int c = 0; c < 8; ++c) {
        f16x8 b = *(const f16x8*)&cbuf[(c * 8 + ds) * 512 + lane * 8];
        acc[0][c] = __builtin_amdgcn_mfma_f32_16x16x32_f16(a16[0][ds], b, acc[0][c], 0, 0, 0);
        acc[1][c] = __builtin_amdgcn_mfma_f32_16x16x32_f16(a16[1][ds], b, acc[1][c], 0, 0, 0);
      }
    }

    __syncthreads();   // all waves done reading cbuf for stage s
    // issue next stage's staging NOW; epilogue+recheck hide its latency
    if (s < NSTG - 1) {
      const short* src = ch_g + (long)(s + 1) * 32768;
#pragma unroll
      for (int j = 0; j < 8; ++j) {
        int off = wv * 4096 + j * 512 + lane * 8;
        gload_lds16(src + off, &cbuf[0] + off);
      }
    }

    // ---- epilogue: dv, emission vs running min, row-min update ----
    // C/D layout: col = lane&15 (code), row = 4*qd + rg (within 16-tile)
    float ccv[8];
#pragma unroll
    for (int c = 0; c < 8; ++c) ccv[c] = cc_s[kbase + 16 * c + l15];
    float rmin[2][4];
#pragma unroll
    for (int m = 0; m < 2; ++m)
#pragma unroll
      for (int rg = 0; rg < 4; ++rg) rmin[m][rg] = __builtin_inff();

#pragma unroll
    for (int m = 0; m < 2; ++m)
#pragma unroll
      for (int c = 0; c < 8; ++c)
#pragma unroll
        for (int rg = 0; rg < 4; ++rg) {
          float dv = fmaf(acc[m][c][rg], -ACC_SCL, ccv[c]);
          if (s > 0 && dv <= runmin[m][rg] + TAU) {
            unsigned idx = atomicAdd(&emit_s[wv][0], 1u);
            if (idx < ECAP) {
              unsigned row = (unsigned)(32 * wv + 16 * m + 4 * qd + rg);
              emit_s[wv][1 + idx] = (row << 10) | (unsigned)(kbase + 16 * c + l15);
            }
          }
          rmin[m][rg] = fminf(rmin[m][rg], dv);
        }
    // reduce rmin over the 16 lanes (codes) of each group
#pragma unroll
    for (int off = 1; off < 16; off <<= 1)
#pragma unroll
      for (int m = 0; m < 2; ++m)
#pragma unroll
        for (int rg = 0; rg < 4; ++rg)
          rmin[m][rg] = fminf(rmin[m][rg], __shfl_xor(rmin[m][rg], off, 64));
#pragma unroll
    for (int m = 0; m < 2; ++m)
#pragma unroll
      for (int rg = 0; rg < 4; ++rg) runmin[m][rg] = fminf(runmin[m][rg], rmin[m][rg]);

    if (s == 0) {
      // stage 0: emit vs its own (now known) chunk min
#pragma unroll
      for (int m = 0; m < 2; ++m)
#pragma unroll
        for (int c = 0; c < 8; ++c)
#pragma unroll
          for (int rg = 0; rg < 4; ++rg) {
            float dv = fmaf(acc[m][c][rg], -ACC_SCL, ccv[c]);
            if (dv <= runmin[m][rg] + TAU) {
              unsigned idx = atomicAdd(&emit_s[wv][0], 1u);
              if (idx < ECAP) {
                unsigned row = (unsigned)(32 * wv + 16 * m + 4 * qd + rg);
                emit_s[wv][1 + idx] = (row << 10) | (unsigned)(kbase + 16 * c + l15);
              }
            }
          }
    }

    // ---- wave-local exact recheck (overlaps next-stage staging) ----
    unsigned cnt = emit_s[wv][0];
    if (cnt <= ECAP) {
      for (unsigned p = (unsigned)lane; p < cnt; p += 64) {
        unsigned e = emit_s[wv][1 + p];
        int rl = (int)(e >> 10), k = (int)(e & 1023);
        float dd = exact_dd(z + (rowbase + rl) * DIM, cb + (long)k * DIM, cc_s[k]);
        atomicMin(&packed[rowbase + rl],
                  ((unsigned long long)__float_as_uint(dd) << 32) | (unsigned)k);
      }
    } else {
      // overflow fallback (never expected): exact scan of wave rows x stage codes
      for (int p = lane; p < 32 * 128; p += 64) {
        int rl = 32 * wv + (p >> 7), k = kbase + (p & 127);
        float dd = exact_dd(z + (rowbase + rl) * DIM, cb + (long)k * DIM, cc_s[k]);
        atomicMin(&packed[rowbase + rl],
                  ((unsigned long long)__float_as_uint(dd) << 32) | (unsigned)k);
      }
    }
    if (lane == 0) emit_s[wv][0] = 0u;

    __syncthreads();   // next stage staged (vmcnt drained) + counters reset
  }
}

// K1b: ids from packed argmin
__global__ void extract_ids(const unsigned long long* __restrict__ packed,
                            float* __restrict__ ids_f) {
  int i = blockIdx.x * blockDim.x + threadIdx.x;
  if (i < N_TOK) ids_f[i] = (float)(unsigned)(packed[i] & 0xFFFFFFFFull);
}

// K2: out0 = z, out1 = codebook[ids], fp64 per-block partial of (zq - z)^2
__global__ void output_kernel(const float* __restrict__ z, const float* __restrict__ cb,
                              const float* __restrict__ ids_f,
                              float* __restrict__ out_z, float* __restrict__ out_zq,
                              double* __restrict__ slots, int nslots) {
  __shared__ double red[4];
  double acc = 0.0;
  const long total4 = (long)N_TOK * DIM / 4;
  long idx    = (long)blockIdx.x * blockDim.x + threadIdx.x;
  long stride = (long)gridDim.x * blockDim.x;
  for (long i = idx; i < total4; i += stride) {
    long e = i * 4;
    long r = e >> 8;
    int  k = (int)ids_f[r];
    float4 vz = *(const float4*)(z + e);
    float4 vc = *(const float4*)(cb + (long)k * DIM + (e & 255));
    *(float4*)(out_z + e)  = vz;
    *(float4*)(out_zq + e) = vc;
    float d0 = vc.x - vz.x, d1 = vc.y - vz.y, d2 = vc.z - vz.z, d3 = vc.w - vz.w;
    acc += (double)(d0 * d0) + (double)(d1 * d1) + (double)(d2 * d2) + (double)(d3 * d3);
  }
#pragma unroll
  for (int off = 32; off > 0; off >>= 1) acc += __shfl_down(acc, off, 64);
  int lane = threadIdx.x & 63, wvv = threadIdx.x >> 6;
  if (lane == 0) red[wvv] = acc;
  __syncthreads();
  if (threadIdx.x == 0) {
    double sum = (red[0] + red[1]) + (red[2] + red[3]);
    if (nslots > 1) slots[blockIdx.x] = sum;   // no same-address contention
    else atomicAdd(&slots[0], sum);
  }
}

// K3: loss = 1.25 * mean((zq - z)^2)
__global__ void finalize_kernel(const double* __restrict__ slots, int nslots,
                                float* __restrict__ out_loss) {
  __shared__ double red[4];
  double a = 0.0;
  for (int i = threadIdx.x; i < nslots; i += 256) a += slots[i];
#pragma unroll
  for (int off = 32; off > 0; off >>= 1) a += __shfl_down(a, off, 64);
  int lane = threadIdx.x & 63, wvv = threadIdx.x >> 6;
  if (lane == 0) red[wvv] = a;
  __syncthreads();
  if (threadIdx.x == 0) {
    double s = (red[0] + red[1]) + (red[2] + red[3]);
    out_loss[0] = (float)(1.25 * (s / (double)((long)N_TOK * DIM)));
  }
}

extern "C" void kernel_launch(void* const* d_in, const int* in_sizes, int n_in,
                              void* d_out, int out_size, void* d_ws, size_t ws_size,
                              hipStream_t stream) {
  const float* z  = (const float*)d_in[0];
  const float* cb = (const float*)d_in[1];
  float* out      = (float*)d_out;
  float* out_z    = out;                              // [N, D]
  float* out_zq   = out + (long)N_TOK * DIM;          // [N, D]
  float* out_ids  = out_zq + (long)N_TOK * DIM;       // [N] as fp32
  float* out_loss = out_ids + N_TOK;                  // [1]

  // loss partials: 2048 slots in ws if it fits, else single atomic cell
  int nslots = (ws_size >= 2048 * sizeof(double)) ? 2048 : 1;
  double* slots = (double*)d_ws;

  // scratch inside the out_z region (dead until output_kernel overwrites it):
  // ch16 (512KB) @0 | cc (4KB) @512K | packed u64 (1MB) @2M
  // all consumed (vq+extract) before output_kernel writes out_z
  short* ch_g = (short*)((char*)d_out);
  float* cc_g = (float*)((char*)d_out + 524288);
  unsigned long long* packed = (unsigned long long*)((char*)d_out + 2097152);

  prep_cc<<<4, 256, 0, stream>>>(cb, cc_g, slots, nslots);
  prep_h16<<<KCB * DIM / 256, 256, 0, stream>>>(cb, ch_g, packed);
  vq_kernel<<<N_TOK / RPB, 512, 0, stream>>>(z, cb, ch_g, cc_g, packed);
  extract_ids<<<N_TOK / 256, 256, 0, stream>>>(packed, out_ids);
  output_kernel<<<2048, 256, 0, stream>>>(z, cb, out_ids, out_z, out_zq, slots, nslots);
  finalize_kernel<<<1, 256, 0, stream>>>(slots, nslots, out_loss);
}